// Round 1
// baseline (675.904 us; speedup 1.0000x reference)
//
#include <hip/hip_runtime.h>
#include <math.h>

#define BATCH 256
#define ISZ 256
#define H 512
#define BH (BATCH * H)       // 131072
#define CLIPV 2.0f

__device__ __forceinline__ float sigmoidf_(float x) { return 1.0f / (1.0f + expf(-x)); }

// ---------------- K1: the small dense GEMMs ----------------
// z=0..2: gate pre-activations  pre = x@x2g_w.T + x2g_b + h0@h2g_w.T + h2g_b
// z=3:    preC = x@x2c_w.T + x2c_b
// z=4:    hw   = h0 @ w          (w is [h,k], k contiguous)
#define BT 64
#define KT 32
#define LDSP (BT + 4)

__global__ __launch_bounds__(256) void small_gemms(
    const float* __restrict__ x, const float* __restrict__ h0,
    const float* __restrict__ x2f_w, const float* __restrict__ x2f_b,
    const float* __restrict__ h2f_w, const float* __restrict__ h2f_b,
    const float* __restrict__ x2i_w, const float* __restrict__ x2i_b,
    const float* __restrict__ h2i_w, const float* __restrict__ h2i_b,
    const float* __restrict__ x2o_w, const float* __restrict__ x2o_b,
    const float* __restrict__ h2o_w, const float* __restrict__ h2o_b,
    const float* __restrict__ x2c_w, const float* __restrict__ x2c_b,
    const float* __restrict__ w,
    float* __restrict__ pre)
{
  __shared__ __align__(16) float As[KT][LDSP];
  __shared__ __align__(16) float Bs[KT][LDSP];
  const int z  = blockIdx.z;
  const int n0 = blockIdx.x * BT;
  const int m0 = blockIdx.y * BT;
  const int t  = threadIdx.x;
  const int tx = t & 15, ty = t >> 4;

  float acc[4][4] = {{0.0f}};

  const float* Aseg[2]; const float* Bseg[2];
  int ldaS[2], KS[2]; int nseg; bool kmajor = true;
  const float* xb = nullptr; const float* hbias = nullptr;

  if (z < 3) {
    const float* xw; const float* hw_;
    if (z == 0)      { xw = x2f_w; xb = x2f_b; hw_ = h2f_w; hbias = h2f_b; }
    else if (z == 1) { xw = x2i_w; xb = x2i_b; hw_ = h2i_w; hbias = h2i_b; }
    else             { xw = x2o_w; xb = x2o_b; hw_ = h2o_w; hbias = h2o_b; }
    Aseg[0] = x;  ldaS[0] = ISZ; Bseg[0] = xw;  KS[0] = ISZ;
    Aseg[1] = h0; ldaS[1] = H;   Bseg[1] = hw_; KS[1] = H;
    nseg = 2;
  } else if (z == 3) {
    Aseg[0] = x; ldaS[0] = ISZ; Bseg[0] = x2c_w; KS[0] = ISZ; xb = x2c_b;
    nseg = 1;
  } else {
    Aseg[0] = h0; ldaS[0] = H; Bseg[0] = w; KS[0] = H;
    nseg = 1; kmajor = false;
  }

  for (int s = 0; s < nseg; ++s) {
    const float* A  = Aseg[s];
    const float* Bm = Bseg[s];
    const int lda = ldaS[s];
    const int K   = KS[s];
    for (int kk0 = 0; kk0 < K; kk0 += KT) {
      // stage A tile [KT x BT] (coalesced over k)
      #pragma unroll
      for (int i = 0; i < 8; ++i) {
        int l = i * 256 + t;
        int j = l & 31, r = l >> 5;
        As[j][r] = A[(size_t)(m0 + r) * lda + kk0 + j];
      }
      // stage B tile
      if (kmajor) {
        #pragma unroll
        for (int i = 0; i < 8; ++i) {
          int l = i * 256 + t;
          int j = l & 31, n = l >> 5;
          Bs[j][n] = Bm[(size_t)(n0 + n) * K + kk0 + j];
        }
      } else {
        #pragma unroll
        for (int i = 0; i < 8; ++i) {
          int l = i * 256 + t;
          int n = l & 63, j = l >> 6;
          Bs[j][n] = Bm[(size_t)(kk0 + j) * H + n0 + n];
        }
      }
      __syncthreads();
      #pragma unroll
      for (int j = 0; j < KT; ++j) {
        float4 a  = *(const float4*)&As[j][ty * 4];
        float4 bv = *(const float4*)&Bs[j][tx * 4];
        float av[4] = {a.x, a.y, a.z, a.w};
        float bw[4] = {bv.x, bv.y, bv.z, bv.w};
        #pragma unroll
        for (int r = 0; r < 4; ++r)
          #pragma unroll
          for (int c = 0; c < 4; ++c)
            acc[r][c] += av[r] * bw[c];
      }
      __syncthreads();
    }
  }

  float bias[4];
  #pragma unroll
  for (int c = 0; c < 4; ++c) {
    int n = n0 + tx * 4 + c;
    float bv = 0.0f;
    if (z < 3)       bv = xb[n] + hbias[n];
    else if (z == 3) bv = xb[n];
    bias[c] = bv;
  }
  float* outc = pre + (size_t)z * BH;
  #pragma unroll
  for (int r = 0; r < 4; ++r) {
    int m = m0 + ty * 4 + r;
    float4 o;
    o.x = acc[r][0] + bias[0];
    o.y = acc[r][1] + bias[1];
    o.z = acc[r][2] + bias[2];
    o.w = acc[r][3] + bias[3];
    *(float4*)&outc[(size_t)m * H + n0 + tx * 4] = o;
  }
}

// ---------------- K2: hb_partial[b,seg,k] = sum_{h in seg} h0[b,h]*hebb[b,h,k] ----------------
// grid (256 b, 8 hsegs of 64), 128 threads, float4 per thread over k.
__global__ __launch_bounds__(128) void einsum_partial(
    const float* __restrict__ h0, const float* __restrict__ hebb,
    float* __restrict__ hbpart)
{
  const int b    = blockIdx.x;
  const int hseg = blockIdx.y;
  const int t    = threadIdx.x;
  __shared__ float h0s[64];
  if (t < 64) h0s[t] = h0[b * H + hseg * 64 + t];
  __syncthreads();

  const float4* hb4 = (const float4*)(hebb + ((size_t)b * H + (size_t)hseg * 64) * H);
  float4 acc = {0.f, 0.f, 0.f, 0.f};
  #pragma unroll 8
  for (int h = 0; h < 64; ++h) {
    float4 v = hb4[(size_t)h * 128 + t];
    float s = h0s[h];
    acc.x += s * v.x; acc.y += s * v.y; acc.z += s * v.z; acc.w += s * v.w;
  }
  ((float4*)(hbpart + ((size_t)(b * 8 + hseg)) * H))[t] = acc;
}

// ---------------- K3: fused gates / cell / hactiv ----------------
__global__ __launch_bounds__(256) void fuse_gates(
    const float* __restrict__ pre, const float* __restrict__ hbpart,
    const float* __restrict__ c0, const float* __restrict__ alpha,
    float* __restrict__ out, float* __restrict__ itc)
{
  const int idx = blockIdx.x * 256 + threadIdx.x;   // b*H + k
  const int k = idx & (H - 1);
  const int b = idx >> 9;
  float hb = 0.0f;
  #pragma unroll
  for (int s = 0; s < 8; ++s) hb += hbpart[((size_t)(b * 8 + s)) * H + k];
  float h2c  = pre[(size_t)4 * BH + idx] + alpha[k] * hb;
  float itcv = tanhf(pre[(size_t)3 * BH + idx] + h2c);
  float f = sigmoidf_(pre[(size_t)0 * BH + idx]);
  float i = sigmoidf_(pre[(size_t)1 * BH + idx]);
  float o = sigmoidf_(pre[(size_t)2 * BH + idx]);
  float cell = f * c0[idx] + i * itcv;
  float ha = o * tanhf(cell);
  out[idx] = ha;
  out[BH + idx] = cell;
  itc[idx] = itcv;
}

// ---------------- K4: m = tanh(hactiv . h2mod_w + b); eta[b,k] = (m*mfo_w[k]+mfo_b[k])*itc[b,k] ----------------
__global__ __launch_bounds__(256) void mod_eta(
    const float* __restrict__ hactiv,
    const float* __restrict__ h2mod_w, const float* __restrict__ h2mod_b,
    const float* __restrict__ mfo_w, const float* __restrict__ mfo_b,
    const float* __restrict__ itc, float* __restrict__ eta)
{
  const int b = blockIdx.x, t = threadIdx.x;
  float s = hactiv[b * H + t] * h2mod_w[t] + hactiv[b * H + 256 + t] * h2mod_w[256 + t];
  #pragma unroll
  for (int off = 32; off > 0; off >>= 1) s += __shfl_down(s, off, 64);
  __shared__ float red[4];
  __shared__ float mm;
  if ((t & 63) == 0) red[t >> 6] = s;
  __syncthreads();
  if (t == 0) mm = tanhf(red[0] + red[1] + red[2] + red[3] + h2mod_b[0]);
  __syncthreads();
  float m = mm;
  #pragma unroll
  for (int kk = t; kk < H; kk += 256) {
    float fan = m * mfo_w[kk] + mfo_b[kk];
    eta[b * H + kk] = fan * itc[b * H + kk];
  }
}

// ---------------- K5: hebb_new = clip(hebb + h0[b,h]*eta[b,k]) ----------------
__global__ __launch_bounds__(256) void hebb_update(
    const float* __restrict__ hebb, const float* __restrict__ h0,
    const float* __restrict__ eta, float* __restrict__ out)
{
  const size_t g = (size_t)blockIdx.x * 256 + threadIdx.x;  // float4 index, 16777216 total
  float4 v = ((const float4*)hebb)[g];
  const int k4  = (int)(g & 127);          // float4 col within row of 512
  const int row = (int)(g >> 7);           // b*512 + h
  const int b   = row >> 9;
  float4 e = ((const float4*)eta)[(b << 7) + k4];
  float s = h0[row];
  float4 r;
  r.x = fminf(fmaxf(v.x + s * e.x, -CLIPV), CLIPV);
  r.y = fminf(fmaxf(v.y + s * e.y, -CLIPV), CLIPV);
  r.z = fminf(fmaxf(v.z + s * e.z, -CLIPV), CLIPV);
  r.w = fminf(fmaxf(v.w + s * e.w, -CLIPV), CLIPV);
  ((float4*)out)[(size_t)(2 * BH / 4) + g] = r;
}

extern "C" void kernel_launch(void* const* d_in, const int* in_sizes, int n_in,
                              void* d_out, int out_size, void* d_ws, size_t ws_size,
                              hipStream_t stream) {
  const float* x       = (const float*)d_in[0];
  const float* h0      = (const float*)d_in[1];
  const float* c0      = (const float*)d_in[2];
  const float* hebb    = (const float*)d_in[3];
  const float* w       = (const float*)d_in[4];
  const float* alpha   = (const float*)d_in[5];
  const float* h2f_w   = (const float*)d_in[6];
  const float* h2f_b   = (const float*)d_in[7];
  const float* h2i_w   = (const float*)d_in[8];
  const float* h2i_b   = (const float*)d_in[9];
  const float* h2o_w   = (const float*)d_in[10];
  const float* h2o_b   = (const float*)d_in[11];
  const float* x2f_w   = (const float*)d_in[12];
  const float* x2f_b   = (const float*)d_in[13];
  const float* x2i_w   = (const float*)d_in[14];
  const float* x2i_b   = (const float*)d_in[15];
  const float* x2o_w   = (const float*)d_in[16];
  const float* x2o_b   = (const float*)d_in[17];
  const float* x2c_w   = (const float*)d_in[18];
  const float* x2c_b   = (const float*)d_in[19];
  const float* h2mod_w = (const float*)d_in[20];
  const float* h2mod_b = (const float*)d_in[21];
  const float* mfo_w   = (const float*)d_in[22];
  const float* mfo_b   = (const float*)d_in[23];

  float* out = (float*)d_out;
  float* ws  = (float*)d_ws;

  float* pre    = ws;                          // 5 * 131072
  float* hbpart = pre + (size_t)5 * BH;        // 256*8*512 = 1048576
  float* itc    = hbpart + (size_t)BATCH * 8 * H;
  float* eta    = itc + BH;                    // total ~7.9 MB

  small_gemms<<<dim3(8, 4, 5), 256, 0, stream>>>(
      x, h0, x2f_w, x2f_b, h2f_w, h2f_b, x2i_w, x2i_b, h2i_w, h2i_b,
      x2o_w, x2o_b, h2o_w, h2o_b, x2c_w, x2c_b, w, pre);

  einsum_partial<<<dim3(BATCH, 8), 128, 0, stream>>>(h0, hebb, hbpart);

  fuse_gates<<<BH / 256, 256, 0, stream>>>(pre, hbpart, c0, alpha, out, itc);

  mod_eta<<<BATCH, 256, 0, stream>>>(out, h2mod_w, h2mod_b, mfo_w, mfo_b, itc, eta);

  hebb_update<<<(BH * H / 4) / 256, 256, 0, stream>>>(hebb, h0, eta, out);
}